// Round 5
// baseline (200.027 us; speedup 1.0000x reference)
//
#include <hip/hip_runtime.h>

// B=16, H=W=64, C=80; tables (127,80) -> reference resize is a no-op.
// Output (B,N,N) fp32 = 1.074 GB: pure HBM write-stream, floor ~168 us.
//
// v4: kill the phase2->phase3 __syncthreads. Token g depends only on wave
// w = g mod 4, so each wave writes rh/rw to a disjoint LDS region, fences
// with a wave-local lgkmcnt(0), and streams its own stores immediately.
// Waves and resident blocks de-synchronize -> store issue stays continuous.
#define HH 64
#define WW 64
#define CC 80
#define NN (HH * WW)
#define G  16          // tokens per block
#define RPW 79         // pw rows needed: ww0 .. ww0+78
#define SP  84         // padded LDS stride: 16B-aligned rows, 8 words/bank

typedef float vf4 __attribute__((ext_vector_type(4)));

__global__ __launch_bounds__(256) void relpos_fused_v4(
    const float* __restrict__ q,    // (B, N, C)
    const float* __restrict__ ph,   // (127, 80)
    const float* __restrict__ pw,   // (127, 80)
    float* __restrict__ out)        // (B, N, N)
{
    __shared__ float sh_q [G * CC];     // 5.0 KB
    __shared__ float sh_pw[RPW * SP];   // 25.9 KB
    __shared__ float sh_dh[G * HH];     // 4.0 KB (per-wave disjoint: g%4==w)
    __shared__ float sh_dw[G * WW];     // 4.0 KB   -> 39.9 KB, 4 blocks/CU

    const int blk = blockIdx.x;          // b*256 + hh*4 + s
    const int s   = blk & 3;
    const int hh  = (blk >> 2) & 63;
    const int b   = blk >> 8;
    const int ww0 = s * G;
    const int t   = threadIdx.x;

    // ---- Phase 1: cooperative staging (the ONLY block barrier) ----
    const vf4* qin4 = reinterpret_cast<const vf4*>(
        q + ((size_t)b * NN + hh * 64 + ww0) * CC);
    vf4* shq4 = reinterpret_cast<vf4*>(sh_q);
    #pragma unroll
    for (int p = t; p < G * CC / 4; p += 256) shq4[p] = qin4[p];

    const vf4* pwsrc = reinterpret_cast<const vf4*>(pw + (size_t)ww0 * CC);
    vf4* shpw4 = reinterpret_cast<vf4*>(sh_pw);
    for (int p = t; p < RPW * (CC / 4); p += 256) {
        const int r  = p / 20;
        const int w4 = p % 20;
        shpw4[r * (SP / 4) + w4] = pwsrc[p];
    }
    __syncthreads();

    // ---- Phase 2 (per wave): dots for tokens g = w + 4k ----
    const int j = t & 63;
    const int w = t >> 6;
    const float* phrow = ph + (size_t)(hh + 63 - j) * CC;  // global gather (L2)

    float acch[4] = {0.f, 0.f, 0.f, 0.f};
    float accw[4] = {0.f, 0.f, 0.f, 0.f};
    #pragma unroll 4
    for (int c = 0; c < CC; c += 4) {
        vf4 hv = *reinterpret_cast<const vf4*>(phrow + c);
        #pragma unroll
        for (int k = 0; k < 4; ++k) {
            const int g = w + 4 * k;
            vf4 qv = *reinterpret_cast<const vf4*>(&sh_q[g * CC + c]);
            vf4 wv = *reinterpret_cast<const vf4*>(
                &sh_pw[(g + 63 - j) * SP + c]);
            acch[k] += qv.x * hv.x + qv.y * hv.y + qv.z * hv.z + qv.w * hv.w;
            accw[k] += qv.x * wv.x + qv.y * wv.y + qv.z * wv.z + qv.w * wv.w;
        }
    }
    #pragma unroll
    for (int k = 0; k < 4; ++k) {
        const int g = w + 4 * k;
        sh_dh[g * HH + j] = acch[k];   // region g%4==w: this wave only
        sh_dw[g * WW + j] = accw[k];
    }
    // Wave-local fence: this wave's ds_writes retire before its ds_reads.
    // (No __syncthreads -- cross-wave regions are disjoint.)
    asm volatile("s_waitcnt lgkmcnt(0)" ::: "memory");
    __builtin_amdgcn_sched_barrier(0);

    // ---- Phase 3 (per wave): stream stores for tokens g = w + 4k ----
    // out[m] = rh[m>>6] + rw[m&63]; f4 p: rh idx = it*4 + (j>>4),
    // rw4 idx = j&15 (2-way bank alias = free; rh 4-addr = 4 banks, free).
    const vf4* dw4 = reinterpret_cast<const vf4*>(sh_dw);
    vf4* out4 = reinterpret_cast<vf4*>(
        out + ((size_t)b * NN + hh * 64 + ww0) * NN);
    #pragma unroll
    for (int k = 0; k < 4; ++k) {
        const int g = w + 4 * k;
        #pragma unroll 4
        for (int it = 0; it < 16; ++it) {
            const int p  = it * 64 + j;
            const float rh = sh_dh[g * HH + (p >> 4)];
            const vf4 wv = dw4[g * 16 + (p & 15)];
            vf4 o;
            o.x = rh + wv.x; o.y = rh + wv.y;
            o.z = rh + wv.z; o.w = rh + wv.w;
            __builtin_nontemporal_store(o, &out4[g * 1024 + p]);
        }
    }
}

extern "C" void kernel_launch(void* const* d_in, const int* in_sizes, int n_in,
                              void* d_out, int out_size, void* d_ws, size_t ws_size,
                              hipStream_t stream) {
    const float* q  = (const float*)d_in[0];
    const float* ph = (const float*)d_in[1];
    const float* pw = (const float*)d_in[2];
    float* out = (float*)d_out;

    const int B = in_sizes[0] / (NN * CC);        // 16
    dim3 grid(B * HH * (WW / G));                  // 4096 blocks
    relpos_fused_v4<<<grid, 256, 0, stream>>>(q, ph, pw, out);
}